// Round 6
// baseline (225.481 us; speedup 1.0000x reference)
//
#include <hip/hip_runtime.h>

// Differentiable histogram: img (128*512*512 f32) -> 256-bin linear-interp hist.
// s = x*255; mass (1-d) to bin b, d to bin b+1; bin 256 dropped.
//
// R6 design (fused single kernel):
//  - R3-R5 established: LDS-atomic path is NOT the bottleneck (halving
//    instructions and halving bank work were both null). Remaining structural
//    overhead: 2nd dispatch + 1MB partial round-trip. Fuse via global u32
//    atomics + last-block-done finalize.
//  - Inner loop: one fixed-point cvt q = trunc(x*65280 + 0.5):
//      b = q>>8, d8 = q&255, keep = (q <= 65280 unsigned).
//    Packed LDS counter (1<<20 | d8), 32 transposed copies (bank = lane&31,
//    conflict-free). h[b] = c[b] - (g8[b]-g8[b-1])/256 per prefix-difference.
//  - Overflow: per-copy count <= 1024 -> packed < 2^30+2^18; global per-bin
//    g8 <= ~34M < 2^32. Safe.
//  - gacc layout (u32, in d_ws): [0..255]=cnt, [256..511]=g8, [512]=ticket.
//    hipMemsetAsync zeroes it each call (graph-safe).

#define NBIN   256
#define NCOPY  32
#define BLK    512
#define GRID   1024
#define SHIFT  20

__global__ __launch_bounds__(BLK) void diffhist_fused(
    const float* __restrict__ img, float* __restrict__ out,
    unsigned* __restrict__ gacc, long long n)
{
    __shared__ unsigned lh[NBIN * NCOPY];   // 32 KB
    __shared__ unsigned s_cnt[NBIN];        //  1 KB
    __shared__ unsigned s_g8[NBIN];         //  1 KB
    __shared__ int is_last;

    const int tid = threadIdx.x;
    const int c   = tid & 31;

    for (int i = tid; i < NBIN * NCOPY; i += BLK) lh[i] = 0u;
    __syncthreads();

    const long long gtid = (long long)blockIdx.x * BLK + tid;
    const long long gsz  = (long long)gridDim.x * BLK;
    const long long n4   = n >> 2;
    const float4* __restrict__ in4 = (const float4*)img;

    auto proc = [&](float x) {
        int q = (int)fmaf(x, 65280.0f, 0.5f);       // round(s*256), s = x*255
        unsigned uq = (unsigned)q;
        const bool keep = (uq <= 65280u);            // x in [0,1] (to 1/512)
        int b = (int)(uq >> 8);
        unsigned inc = (1u << SHIFT) | (uq & 255u);
        b   = keep ? b   : 0;
        inc = keep ? inc : 0u;
        atomicAdd(&lh[(b << 5) + c], inc);           // native ds_add_u32
    };

    long long i = gtid;
    for (; i + 3 * gsz < n4; i += 4 * gsz) {         // 4x float4 per iter
        float4 a  = in4[i];
        float4 b4 = in4[i + gsz];
        float4 c4 = in4[i + 2 * gsz];
        float4 d4 = in4[i + 3 * gsz];
        proc(a.x);  proc(a.y);  proc(a.z);  proc(a.w);
        proc(b4.x); proc(b4.y); proc(b4.z); proc(b4.w);
        proc(c4.x); proc(c4.y); proc(c4.z); proc(c4.w);
        proc(d4.x); proc(d4.y); proc(d4.z); proc(d4.w);
    }
    for (; i < n4; i += gsz) {
        float4 a = in4[i];
        proc(a.x); proc(a.y); proc(a.z); proc(a.w);
    }
    for (long long j = (n4 << 2) + gtid; j < n; j += gsz)   // n % 4 tail
        proc(img[j]);

    __syncthreads();

    // Per-block per-bin sums of the 32 copies -> global u32 atomics.
    if (tid < NBIN) {
        unsigned cs = 0u, gs = 0u;
        #pragma unroll
        for (int k = 0; k < NCOPY; ++k) {
            unsigned t = lh[(tid << 5) + ((tid + k) & 31)];  // rotated
            cs += t >> SHIFT;
            gs += t & ((1u << SHIFT) - 1u);
        }
        atomicAdd(&gacc[tid], cs);
        atomicAdd(&gacc[NBIN + tid], gs);
    }
    __threadfence();            // bin atomics visible before ticket
    __syncthreads();
    if (tid == 0)
        is_last = (atomicAdd(&gacc[2 * NBIN], 1u) == (unsigned)gridDim.x - 1u);
    __syncthreads();

    if (is_last) {
        if (tid < NBIN) {
            s_cnt[tid] = atomicAdd(&gacc[tid], 0u);        // device-scope read
            s_g8[tid]  = atomicAdd(&gacc[NBIN + tid], 0u);
        }
        __syncthreads();
        if (tid < NBIN) {
            float gb = (float)s_g8[tid];
            float gp = (tid > 0) ? (float)s_g8[tid - 1] : 0.0f;
            out[tid] = (float)s_cnt[tid] - (gb - gp) * (1.0f / 256.0f);
        }
    }
}

extern "C" void kernel_launch(void* const* d_in, const int* in_sizes, int n_in,
                              void* d_out, int out_size, void* d_ws, size_t ws_size,
                              hipStream_t stream) {
    const float* img = (const float*)d_in[0];
    float* out = (float*)d_out;
    unsigned* gacc = (unsigned*)d_ws;
    const long long n = (long long)in_sizes[0];

    // Zero cnt[256] + g8[256] + ticket (graph-capture-safe stream memset).
    hipMemsetAsync(gacc, 0, (2 * NBIN + 1) * sizeof(unsigned), stream);

    diffhist_fused<<<GRID, BLK, 0, stream>>>(img, out, gacc, n);
}

// Round 7
// 31.002 us; speedup vs baseline: 7.2732x; 7.2732x over previous
//
#include <hip/hip_runtime.h>

// Differentiable histogram: img (128*512*512 f32) -> 256-bin linear-interp hist.
// s = x*255; split (1-frac, frac) between bins b and b+1; bin 256 dropped.
//
// R7 = exact revert to R3 (best measured: 30.85 us).
// Ledger: R3 30.9 | R4 (u64 atomic, halved instrs) 31.3 null | R5 (u32 packed,
// halved bank work) 32.6 null | R6 (fused single-kernel) 225 REGRESSION
// (319 us even with ~0 HBM traffic -> internal serialization, not memory).
// Conclusion: native int LDS atomics + two-kernel reduce is the optimum
// structure; the ~31 us = 134 MB stream at ~5.4 TB/s effective (half
// L3-served; harness's 512 MB ws-poison evicts the rest) + ~5 us structure.

#define NBIN   256
#define NB1    257      // + overflow slot for b+1 == 256
#define NCOPY  32
#define BLK1   512
#define GRID1  1024
#define BLK2   256

__global__ __launch_bounds__(BLK1) void diffhist_partial(
    const float* __restrict__ img, float* __restrict__ partial, long long n)
{
    // 257 bins x 32 copies, transposed: element (bin,c) at lh[bin*32 + c].
    __shared__ unsigned lh[NB1 * NCOPY];   // 32,896 B

    const int tid = threadIdx.x;
    const int c   = tid & 31;

    for (int i = tid; i < NB1 * NCOPY; i += BLK1) lh[i] = 0u;
    __syncthreads();

    const long long gtid = (long long)blockIdx.x * BLK1 + tid;
    const long long gsz  = (long long)gridDim.x * BLK1;
    const long long n4   = n >> 2;
    const float4* __restrict__ in4 = (const float4*)img;

    for (long long i = gtid; i < n4; i += gsz) {
        float4 v = in4[i];
        #pragma unroll
        for (int k = 0; k < 4; ++k) {
            float x = (k == 0) ? v.x : (k == 1) ? v.y : (k == 2) ? v.z : v.w;
            if (x >= 0.0f && x <= 1.0f) {
                float s = x * 255.0f;
                float f = floorf(s);
                float d = s - f;
                int   b = (int)f;
                unsigned w1 = (unsigned)(d * 65536.0f + 0.5f);  // [0, 65536]
                unsigned w0 = 65536u - w1;
                atomicAdd(&lh[b * NCOPY + c],       w0);   // native ds_add_u32
                atomicAdd(&lh[(b + 1) * NCOPY + c], w1);
            }
        }
    }
    // tail (n divisible by 4 in practice)
    for (long long i = (n4 << 2) + gtid; i < n; i += gsz) {
        float x = img[i];
        if (x >= 0.0f && x <= 1.0f) {
            float s = x * 255.0f;
            float f = floorf(s);
            float d = s - f;
            int   b = (int)f;
            unsigned w1 = (unsigned)(d * 65536.0f + 0.5f);
            unsigned w0 = 65536u - w1;
            atomicAdd(&lh[b * NCOPY + c],       w0);
            atomicAdd(&lh[(b + 1) * NCOPY + c], w1);
        }
    }

    __syncthreads();

    // Reduce 16... (32) copies per bin (u64 accumulate, exact), emit fp32 partial.
    if (tid < NBIN) {
        unsigned long long s = 0ull;
        #pragma unroll
        for (int k = 0; k < NCOPY; ++k) {
            s += (unsigned long long)lh[tid * NCOPY + ((tid + k) & 31)];
        }
        partial[(long long)tid * gridDim.x + blockIdx.x] =
            (float)((double)s * (1.0 / 65536.0));
    }
}

__global__ __launch_bounds__(BLK2) void diffhist_reduce(
    const float* __restrict__ partial, float* __restrict__ out, int G)
{
    const int b = blockIdx.x;                 // bin
    const float* __restrict__ p = partial + (long long)b * G;

    float s = 0.0f;
    for (int i = threadIdx.x; i < G; i += BLK2) s += p[i];

    #pragma unroll
    for (int off = 32; off > 0; off >>= 1) s += __shfl_down(s, off, 64);

    __shared__ float wsum[BLK2 / 64];
    const int wave = threadIdx.x >> 6;
    const int lane = threadIdx.x & 63;
    if (lane == 0) wsum[wave] = s;
    __syncthreads();
    if (threadIdx.x == 0) {
        float tot = 0.0f;
        #pragma unroll
        for (int w = 0; w < BLK2 / 64; ++w) tot += wsum[w];
        out[b] = tot;
    }
}

extern "C" void kernel_launch(void* const* d_in, const int* in_sizes, int n_in,
                              void* d_out, int out_size, void* d_ws, size_t ws_size,
                              hipStream_t stream) {
    const float* img = (const float*)d_in[0];
    float* out = (float*)d_out;
    float* partial = (float*)d_ws;
    const long long n = (long long)in_sizes[0];

    int G = GRID1;
    size_t need = (size_t)G * NBIN * sizeof(float);
    if (ws_size < need) {
        G = (int)(ws_size / ((size_t)NBIN * sizeof(float)));
        if (G < 1) G = 1;
    }

    diffhist_partial<<<G, BLK1, 0, stream>>>(img, partial, n);
    // d_out fully overwritten by reduce kernel (no memset needed).
    diffhist_reduce<<<NBIN, BLK2, 0, stream>>>(partial, out, G);
}

// Round 8
// 30.099 us; speedup vs baseline: 7.4913x; 1.0300x over previous
//
#include <hip/hip_runtime.h>

// Differentiable histogram: img (128*512*512 f32) -> 256-bin linear-interp hist.
// s = x*255; split (1-frac, frac) between bins b and b+1; bin 256 dropped.
//
// R8 = R3/R7 partial kernel (verbatim, proven 31.0 us) + trimmed reduce:
//   reduce reads exactly one float4 per thread (256 thr x 16 B = 1024
//   partials/bin), full-wave shuffle reduce, no per-thread loop.
// Ledger: R3/R7 31.0 | R4 null | R5 null | R6 (global atomics) 225 REGRESSION
//   -> global atomics to few addresses cost ~250 cyc/RMW serialized; never.
// Partial kernel is memory-bound: 134 MB @ ~5.4 TB/s eff (half L3-served),
// DS/VALU proven non-critical (R4/R5). This round trims the ~6 us structure.

#define NBIN   256
#define NB1    257      // + overflow slot for b+1 == 256
#define NCOPY  32
#define BLK1   512
#define GRID1  1024     // reduce kernel assumes exactly 1024 partials per bin
#define BLK2   256

__global__ __launch_bounds__(BLK1) void diffhist_partial(
    const float* __restrict__ img, float* __restrict__ partial, long long n)
{
    // 257 bins x 32 copies, transposed: element (bin,c) at lh[bin*32 + c].
    __shared__ unsigned lh[NB1 * NCOPY];   // 32,896 B

    const int tid = threadIdx.x;
    const int c   = tid & 31;

    for (int i = tid; i < NB1 * NCOPY; i += BLK1) lh[i] = 0u;
    __syncthreads();

    const long long gtid = (long long)blockIdx.x * BLK1 + tid;
    const long long gsz  = (long long)gridDim.x * BLK1;
    const long long n4   = n >> 2;
    const float4* __restrict__ in4 = (const float4*)img;

    for (long long i = gtid; i < n4; i += gsz) {
        float4 v = in4[i];
        #pragma unroll
        for (int k = 0; k < 4; ++k) {
            float x = (k == 0) ? v.x : (k == 1) ? v.y : (k == 2) ? v.z : v.w;
            if (x >= 0.0f && x <= 1.0f) {
                float s = x * 255.0f;
                float f = floorf(s);
                float d = s - f;
                int   b = (int)f;
                unsigned w1 = (unsigned)(d * 65536.0f + 0.5f);  // [0, 65536]
                unsigned w0 = 65536u - w1;
                atomicAdd(&lh[b * NCOPY + c],       w0);   // native ds_add_u32
                atomicAdd(&lh[(b + 1) * NCOPY + c], w1);
            }
        }
    }
    // tail (n divisible by 4 in practice)
    for (long long i = (n4 << 2) + gtid; i < n; i += gsz) {
        float x = img[i];
        if (x >= 0.0f && x <= 1.0f) {
            float s = x * 255.0f;
            float f = floorf(s);
            float d = s - f;
            int   b = (int)f;
            unsigned w1 = (unsigned)(d * 65536.0f + 0.5f);
            unsigned w0 = 65536u - w1;
            atomicAdd(&lh[b * NCOPY + c],       w0);
            atomicAdd(&lh[(b + 1) * NCOPY + c], w1);
        }
    }

    __syncthreads();

    // Reduce 32 copies per bin (u64 accumulate, exact), emit fp32 partial.
    if (tid < NBIN) {
        unsigned long long s = 0ull;
        #pragma unroll
        for (int k = 0; k < NCOPY; ++k) {
            s += (unsigned long long)lh[tid * NCOPY + ((tid + k) & 31)];
        }
        partial[(long long)tid * gridDim.x + blockIdx.x] =
            (float)((double)s * (1.0 / 65536.0));
    }
}

__global__ __launch_bounds__(BLK2) void diffhist_reduce(
    const float* __restrict__ partial, float* __restrict__ out)
{
    // One block per bin; 256 threads x one float4 = 1024 partials.
    const int b = blockIdx.x;
    const float4* __restrict__ p4 =
        (const float4*)(partial + (long long)b * GRID1);

    float4 v = p4[threadIdx.x];
    float s = (v.x + v.y) + (v.z + v.w);

    #pragma unroll
    for (int off = 32; off > 0; off >>= 1) s += __shfl_down(s, off, 64);

    __shared__ float wsum[BLK2 / 64];
    const int wave = threadIdx.x >> 6;
    const int lane = threadIdx.x & 63;
    if (lane == 0) wsum[wave] = s;
    __syncthreads();
    if (threadIdx.x == 0) {
        float tot = 0.0f;
        #pragma unroll
        for (int w = 0; w < BLK2 / 64; ++w) tot += wsum[w];
        out[b] = tot;
    }
}

extern "C" void kernel_launch(void* const* d_in, const int* in_sizes, int n_in,
                              void* d_out, int out_size, void* d_ws, size_t ws_size,
                              hipStream_t stream) {
    const float* img = (const float*)d_in[0];
    float* out = (float*)d_out;
    float* partial = (float*)d_ws;
    const long long n = (long long)in_sizes[0];

    // ws requirement: GRID1 * NBIN * 4 = 1 MB (harness ws is far larger).
    diffhist_partial<<<GRID1, BLK1, 0, stream>>>(img, partial, n);
    // d_out fully overwritten by reduce kernel (no memset needed).
    diffhist_reduce<<<NBIN, BLK2, 0, stream>>>(partial, out);
}